// Round 4
// baseline (2209.557 us; speedup 1.0000x reference)
//
#include <hip/hip_runtime.h>
#include <math.h>

// Block-circulant SwiGLU FFN via per-wave radix-8 FFT-512 (CirCNN style).
// d_model=2048 (p=4 blocks), d_ff=5632 (q=11 blocks), BLOCK=512.
// Round-4: (a) NO explicit LDS fences -- DS ops from one wave are processed
// in order by the LDS pipe, and the compiler inserts minimal lgkmcnt(N) for
// data returns; all FFT hazards are same-wave. (b) sHf staging replaced by a
// shared Z accumulator via fire-and-forget ds_add_f32 -> LDS 46.9->32.1 KB
// -> 4 blocks/CU (4 waves/SIMD).

// LDS element-index swizzle: every access pattern used here (stage reads
// l+64q, writes 8l+m / 64a+b+8m / l+64m, einsum k and 512-k) is GF(2)-linear
// rank-4 in lane bits -> uniform 4 lanes per bank pair (b64 minimum).
__device__ __forceinline__ int swz(int n) { return n ^ ((n >> 3) & 15); }

struct Tw { float t0r[7], t0i[7], t1r[7], t1i[7]; };

// Per-lane register twiddles: stage0 W512^{l*m}, stage1 W512^{8*(l>>3)*m}.
__device__ __forceinline__ void make_tw(int l, Tw& T)
{
    float c0, s0;
    __sincosf(-6.283185307179586f * (float)l * (1.0f/512.0f), &s0, &c0);
    float pr = c0, pi = s0;
    T.t0r[0] = pr; T.t0i[0] = pi;
#pragma unroll
    for (int m = 1; m < 7; ++m) {
        float nr = pr*c0 - pi*s0, ni = pr*s0 + pi*c0;
        pr = nr; pi = ni;
        T.t0r[m] = pr; T.t0i[m] = pi;
    }
    float c1, s1;
    __sincosf(-6.283185307179586f * (float)(l >> 3) * (1.0f/64.0f), &s1, &c1);
    pr = c1; pi = s1;
    T.t1r[0] = pr; T.t1i[0] = pi;
#pragma unroll
    for (int m = 1; m < 7; ++m) {
        float nr = pr*c1 - pi*s1, ni = pr*s1 + pi*c1;
        pr = nr; pi = ni;
        T.t1r[m] = pr; T.t1i[m] = pi;
    }
}

// 8-point DFT (DIF): A_m = sum_q a_q w8^{qm}, w8 = e^{-2pi i/8} (conj if INV).
template<bool INV>
__device__ __forceinline__ void dft8(float xr[8], float xi[8])
{
    const float C = 0.70710678118654752f;
    float tr[4], ti[4], ur[4], ui[4];
#pragma unroll
    for (int q = 0; q < 4; ++q) {
        tr[q] = xr[q] + xr[q+4];  ti[q] = xi[q] + xi[q+4];
        ur[q] = xr[q] - xr[q+4];  ui[q] = xi[q] - xi[q+4];
    }
    {
        float xx = ur[1], yy = ui[1];
        if (!INV) { ur[1] = C*(xx+yy); ui[1] = C*(yy-xx); }
        else      { ur[1] = C*(xx-yy); ui[1] = C*(xx+yy); }
    }
    {
        float xx = ur[2], yy = ui[2];
        if (!INV) { ur[2] = yy;  ui[2] = -xx; }
        else      { ur[2] = -yy; ui[2] = xx; }
    }
    {
        float xx = ur[3], yy = ui[3];
        if (!INV) { ur[3] = C*(yy-xx);  ui[3] = -C*(xx+yy); }
        else      { ur[3] = -C*(xx+yy); ui[3] = C*(xx-yy); }
    }
    {
        float s0r=tr[0]+tr[2], s0i=ti[0]+ti[2];
        float d0r=tr[0]-tr[2], d0i=ti[0]-ti[2];
        float s1r=tr[1]+tr[3], s1i=ti[1]+ti[3];
        float e1r=tr[1]-tr[3], e1i=ti[1]-ti[3];
        float d1r, d1i;
        if (!INV) { d1r = e1i;  d1i = -e1r; } else { d1r = -e1i; d1i = e1r; }
        xr[0]=s0r+s1r; xi[0]=s0i+s1i;
        xr[2]=d0r+d1r; xi[2]=d0i+d1i;
        xr[4]=s0r-s1r; xi[4]=s0i-s1i;
        xr[6]=d0r-d1r; xi[6]=d0i-d1i;
    }
    {
        float s0r=ur[0]+ur[2], s0i=ui[0]+ui[2];
        float d0r=ur[0]-ur[2], d0i=ui[0]-ui[2];
        float s1r=ur[1]+ur[3], s1i=ui[1]+ui[3];
        float e1r=ur[1]-ur[3], e1i=ui[1]-ui[3];
        float d1r, d1i;
        if (!INV) { d1r = e1i;  d1i = -e1r; } else { d1r = -e1i; d1i = e1r; }
        xr[1]=s0r+s1r; xi[1]=s0i+s1i;
        xr[3]=d0r+d1r; xi[3]=d0i+d1i;
        xr[5]=s0r-s1r; xi[5]=s0i-s1i;
        xr[7]=d0r-d1r; xi[7]=d0i-d1i;
    }
}

// In-place radix-8 Stockham FFT-512 on a wave-private (swizzled) LDS buffer.
// Natural-order in/out; forward = e^{-i}, INV = conjugated (unscaled inverse).
// No explicit fences: same-wave DS ops are processed in order by the LDS
// pipe; compiler inserts lgkmcnt(N) for the data-return dependencies.
template<bool INV>
__device__ __forceinline__ void fft512_r8(float2* wk, int l, const Tw& T)
{
    float xr[8], xi[8];
    // ---- stage 0 (s=1): twiddle W^{l*m} ----
#pragma unroll
    for (int q = 0; q < 8; ++q) { float2 v = wk[swz(l + 64*q)]; xr[q]=v.x; xi[q]=v.y; }
    dft8<INV>(xr, xi);
#pragma unroll
    for (int m = 1; m < 8; ++m) {
        float wr = T.t0r[m-1], wi = INV ? -T.t0i[m-1] : T.t0i[m-1];
        float nr = xr[m]*wr - xi[m]*wi, ni = xr[m]*wi + xi[m]*wr;
        xr[m]=nr; xi[m]=ni;
    }
#pragma unroll
    for (int m = 0; m < 8; ++m) wk[swz(8*l + m)] = make_float2(xr[m], xi[m]);
    // ---- stage 1 (s=8): twiddle W^{8*(l>>3)*m} ----
#pragma unroll
    for (int q = 0; q < 8; ++q) { float2 v = wk[swz(l + 64*q)]; xr[q]=v.x; xi[q]=v.y; }
    dft8<INV>(xr, xi);
#pragma unroll
    for (int m = 1; m < 8; ++m) {
        float wr = T.t1r[m-1], wi = INV ? -T.t1i[m-1] : T.t1i[m-1];
        float nr = xr[m]*wr - xi[m]*wi, ni = xr[m]*wi + xi[m]*wr;
        xr[m]=nr; xi[m]=ni;
    }
    {
        const int base = 64*(l>>3) + (l&7);
#pragma unroll
        for (int m = 0; m < 8; ++m) wk[swz(base + 8*m)] = make_float2(xr[m], xi[m]);
    }
    // ---- stage 2 (s=64): no twiddle ----
#pragma unroll
    for (int q = 0; q < 8; ++q) { float2 v = wk[swz(l + 64*q)]; xr[q]=v.x; xi[q]=v.y; }
    dft8<INV>(xr, xi);
#pragma unroll
    for (int m = 0; m < 8; ++m) wk[swz(l + 64*m)] = make_float2(xr[m], xi[m]);
}

// ---------------- weight spectra precompute: one wave per weight block ----------------
// wsp (float2): blocks 0..43 = rfft(wg)/512 (idx q*4+p), 44..87 = rfft(wu)/512,
// 88..131 = rfft(wd)/512 (idx p*11+q). 257 entries per block.
__global__ __launch_bounds__(64) void wf_prep(const float* __restrict__ wg,
                                              const float* __restrict__ wu,
                                              const float* __restrict__ wd,
                                              float2* __restrict__ wsp)
{
    __shared__ float2 wk[512];
    const int t = threadIdx.x;
    Tw T; make_tw(t, T);
    const int b = blockIdx.x;      // 0..131
    const float* src = (b < 44) ? (wg + (size_t)b * 512)
                     : (b < 88) ? (wu + (size_t)(b - 44) * 512)
                                : (wd + (size_t)(b - 88) * 512);
    float2* dst = wsp + (size_t)b * 257;

#pragma unroll
    for (int i = 0; i < 8; ++i) { int n = t + 64*i; wk[swz(n)] = make_float2(src[n], 0.f); }
    fft512_r8<false>(wk, t, T);
    const float sc = 1.0f / 512.0f;   // fold irfft 1/N into the weight spectrum
#pragma unroll
    for (int i = 0; i < 5; ++i) {
        int k = t + 64*i;
        if (k <= 256) { float2 z = wk[swz(k)]; dst[k] = make_float2(sc*z.x, sc*z.y); }
    }
}

// ---------------- fused FFN: one 256-thread block per row ----------------
__global__ __launch_bounds__(256) void bcffn(const float* __restrict__ x,
                                             const float2* __restrict__ wsp,
                                             float* __restrict__ out)
{
    __shared__ float2 sWork[4 * 512];   // 16 KB    per-wave FFT buffers (swizzled)
    __shared__ float2 sXf[4][257];      //  8.2 KB  X spectra (half, Hermitian)
    __shared__ float  sZr[4 * 257];     //  4.1 KB  down-proj accumulator (re)
    __shared__ float  sZi[4 * 257];     //  4.1 KB                         (im)
                                        // 32.1 KB -> 4 blocks/CU

    const int tid = threadIdx.x;
    const int t = tid & 63, w = tid >> 6;
    const size_t row = blockIdx.x;

    Tw T; make_tw(t, T);

    // zero the Z accumulator (visible to all waves after the P1 barrier)
    for (int i = tid; i < 1028; i += 256) { sZr[i] = 0.f; sZi[i] = 0.f; }

    const float2* Wg = wsp;
    const float2* Wu = wsp + 44 * 257;
    const float2* Wd = wsp + 88 * 257;

    float2* wk = sWork + (w << 9);

    // ---- P1: wave w: FFT of x block w (imag = 0) ----
    {
        const float4* x4 = (const float4*)(x + row * 2048 + (size_t)w * 512);
#pragma unroll
        for (int u = 0; u < 2; ++u) {
            int e = t + 64*u;
            float4 a = x4[e];
            int n = 4*e;
            wk[swz(n+0)] = make_float2(a.x, 0.f);
            wk[swz(n+1)] = make_float2(a.y, 0.f);
            wk[swz(n+2)] = make_float2(a.z, 0.f);
            wk[swz(n+3)] = make_float2(a.w, 0.f);
        }
    }
    fft512_r8<false>(wk, t, T);
#pragma unroll
    for (int u = 0; u < 5; ++u) {
        int k = t + 64*u;
        if (k <= 256) sXf[w][k] = wk[swz(k)];
    }
    __syncthreads();

    // ---- P2: per q: einsum -> packed iFFT(G+iU) -> h=silu(g)*u -> FFT(h)
    //      -> accumulate Z[p] += Hf*Wd[p,q] via fire-and-forget ds_add_f32 ----
#pragma unroll 1
    for (int r = 0; r < 3; ++r) {
        const int q = r * 4 + w;
        if (q < 11) {
#pragma unroll
            for (int u = 0; u < 5; ++u) {
                int k = t + 64*u;
                if (k <= 256) {
                    float gr=0.f, gi=0.f, ur_=0.f, ui_=0.f;
#pragma unroll
                    for (int p = 0; p < 4; ++p) {
                        float2 X = sXf[p][k];
                        float2 a = Wg[(q*4 + p)*257 + k];
                        float2 b = Wu[(q*4 + p)*257 + k];
                        gr  += X.x*a.x - X.y*a.y;  gi  += X.x*a.y + X.y*a.x;
                        ur_ += X.x*b.x - X.y*b.y;  ui_ += X.x*b.y + X.y*b.x;
                    }
                    // packed spectrum Z = G + i*U  (z = g + i*u in time domain)
                    wk[swz(k)] = make_float2(gr - ui_, gi + ur_);
                    if (k != 0 && k != 256)
                        wk[swz(512 - k)] = make_float2(gr + ui_, ur_ - gi);
                }
            }
            fft512_r8<true>(wk, t, T);     // unscaled inverse; 1/512 lives in W
#pragma unroll
            for (int u = 0; u < 8; ++u) {
                int n = t + 64*u;
                float2 v = wk[swz(n)];
                float h = v.x * v.y / (1.f + __expf(-v.x));   // silu(g)*u
                wk[swz(n)] = make_float2(h, 0.f);             // same-lane RMW
            }
            fft512_r8<false>(wk, t, T);
#pragma unroll
            for (int u = 0; u < 5; ++u) {
                int k = t + 64*u;
                if (k <= 256) {
                    float2 H = wk[swz(k)];
#pragma unroll
                    for (int p = 0; p < 4; ++p) {
                        float2 d = Wd[(p*11 + q)*257 + k];
                        atomicAdd(&sZr[p*257 + k], H.x*d.x - H.y*d.y);
                        atomicAdd(&sZi[p*257 + k], H.x*d.y + H.y*d.x);
                    }
                }
            }
        }
    }
    __syncthreads();

    // ---- P3: wave w = output block p: iFFT of Z[w] ----
#pragma unroll
    for (int u = 0; u < 5; ++u) {
        int k = t + 64*u;
        if (k <= 256) {
            float zr = sZr[w*257 + k], zi = sZi[w*257 + k];
            wk[swz(k)] = make_float2(zr, zi);
            if (k != 0 && k != 256)
                wk[swz(512 - k)] = make_float2(zr, -zi);
        }
    }
    fft512_r8<true>(wk, t, T);
    {
        float4* o4 = (float4*)(out + row * 2048 + (size_t)w * 512);
#pragma unroll
        for (int u = 0; u < 2; ++u) {
            int e = t + 64*u;
            int n = 4*e;
            o4[e] = make_float4(wk[swz(n)].x, wk[swz(n+1)].x,
                                wk[swz(n+2)].x, wk[swz(n+3)].x);
        }
    }
}

extern "C" void kernel_launch(void* const* d_in, const int* in_sizes, int n_in,
                              void* d_out, int out_size, void* d_ws, size_t ws_size,
                              hipStream_t stream)
{
    (void)n_in; (void)out_size; (void)ws_size;
    const float* x  = (const float*)d_in[0];
    const float* wg = (const float*)d_in[1];
    const float* wu = (const float*)d_in[2];
    const float* wd = (const float*)d_in[3];
    float2* wsp = (float2*)d_ws;          // 132*257 float2 = 271 KB used
    float*  out = (float*)d_out;

    const int rows = in_sizes[0] / 2048;  // 16384

    wf_prep<<<132, 64, 0, stream>>>(wg, wu, wd, wsp);
    bcffn<<<rows, 256, 0, stream>>>(x, wsp, out);
}

// Round 5
// 668.370 us; speedup vs baseline: 3.3059x; 3.3059x over previous
//
#include <hip/hip_runtime.h>
#include <math.h>

// Block-circulant SwiGLU FFN via per-wave radix-8 FFT-512 (CirCNN style).
// d_model=2048 (p=4 blocks), d_ff=5632 (q=11 blocks), BLOCK=512.
// Round-5: round-3 verified base (fenced radix-8 FFT, no atomics) + ONE
// change: sHf[11] staging -> rotating sHf[4] + per-wave REGISTER Z
// accumulation (each wave owns output block p=w). LDS 46.9 -> 32.1 KB
// -> 4 blocks/CU. LDS float atomics avoided (CAS-loop poison, R2/R4).

#define WAVE_FENCE() do { asm volatile("s_waitcnt lgkmcnt(0)" ::: "memory"); \
                          __builtin_amdgcn_sched_barrier(0); } while (0)

// LDS element-index swizzle: every access pattern used here (stage reads
// l+64q, writes 8l+m / 64a+b+8m / l+64m, einsum k and 512-k) is GF(2)-linear
// rank-4 in lane bits -> uniform 4 lanes per bank pair (b64 minimum).
__device__ __forceinline__ int swz(int n) { return n ^ ((n >> 3) & 15); }

struct Tw { float t0r[7], t0i[7], t1r[7], t1i[7]; };

// Per-lane register twiddles: stage0 W512^{l*m}, stage1 W512^{8*(l>>3)*m}.
__device__ __forceinline__ void make_tw(int l, Tw& T)
{
    float c0, s0;
    __sincosf(-6.283185307179586f * (float)l * (1.0f/512.0f), &s0, &c0);
    float pr = c0, pi = s0;
    T.t0r[0] = pr; T.t0i[0] = pi;
#pragma unroll
    for (int m = 1; m < 7; ++m) {
        float nr = pr*c0 - pi*s0, ni = pr*s0 + pi*c0;
        pr = nr; pi = ni;
        T.t0r[m] = pr; T.t0i[m] = pi;
    }
    float c1, s1;
    __sincosf(-6.283185307179586f * (float)(l >> 3) * (1.0f/64.0f), &s1, &c1);
    pr = c1; pi = s1;
    T.t1r[0] = pr; T.t1i[0] = pi;
#pragma unroll
    for (int m = 1; m < 7; ++m) {
        float nr = pr*c1 - pi*s1, ni = pr*s1 + pi*c1;
        pr = nr; pi = ni;
        T.t1r[m] = pr; T.t1i[m] = pi;
    }
}

// 8-point DFT (DIF): A_m = sum_q a_q w8^{qm}, w8 = e^{-2pi i/8} (conj if INV).
template<bool INV>
__device__ __forceinline__ void dft8(float xr[8], float xi[8])
{
    const float C = 0.70710678118654752f;
    float tr[4], ti[4], ur[4], ui[4];
#pragma unroll
    for (int q = 0; q < 4; ++q) {
        tr[q] = xr[q] + xr[q+4];  ti[q] = xi[q] + xi[q+4];
        ur[q] = xr[q] - xr[q+4];  ui[q] = xi[q] - xi[q+4];
    }
    {
        float xx = ur[1], yy = ui[1];
        if (!INV) { ur[1] = C*(xx+yy); ui[1] = C*(yy-xx); }
        else      { ur[1] = C*(xx-yy); ui[1] = C*(xx+yy); }
    }
    {
        float xx = ur[2], yy = ui[2];
        if (!INV) { ur[2] = yy;  ui[2] = -xx; }
        else      { ur[2] = -yy; ui[2] = xx; }
    }
    {
        float xx = ur[3], yy = ui[3];
        if (!INV) { ur[3] = C*(yy-xx);  ui[3] = -C*(xx+yy); }
        else      { ur[3] = -C*(xx+yy); ui[3] = C*(xx-yy); }
    }
    {
        float s0r=tr[0]+tr[2], s0i=ti[0]+ti[2];
        float d0r=tr[0]-tr[2], d0i=ti[0]-ti[2];
        float s1r=tr[1]+tr[3], s1i=ti[1]+ti[3];
        float e1r=tr[1]-tr[3], e1i=ti[1]-ti[3];
        float d1r, d1i;
        if (!INV) { d1r = e1i;  d1i = -e1r; } else { d1r = -e1i; d1i = e1r; }
        xr[0]=s0r+s1r; xi[0]=s0i+s1i;
        xr[2]=d0r+d1r; xi[2]=d0i+d1i;
        xr[4]=s0r-s1r; xi[4]=s0i-s1i;
        xr[6]=d0r-d1r; xi[6]=d0i-d1i;
    }
    {
        float s0r=ur[0]+ur[2], s0i=ui[0]+ui[2];
        float d0r=ur[0]-ur[2], d0i=ui[0]-ui[2];
        float s1r=ur[1]+ur[3], s1i=ui[1]+ui[3];
        float e1r=ur[1]-ur[3], e1i=ui[1]-ui[3];
        float d1r, d1i;
        if (!INV) { d1r = e1i;  d1i = -e1r; } else { d1r = -e1i; d1i = e1r; }
        xr[1]=s0r+s1r; xi[1]=s0i+s1i;
        xr[3]=d0r+d1r; xi[3]=d0i+d1i;
        xr[5]=s0r-s1r; xi[5]=s0i-s1i;
        xr[7]=d0r-d1r; xi[7]=d0i-d1i;
    }
}

// In-place radix-8 Stockham FFT-512 on a wave-private (swizzled) LDS buffer.
// Natural-order in/out; forward = e^{-i}, INV = conjugated (unscaled inverse).
template<bool INV>
__device__ __forceinline__ void fft512_r8(float2* wk, int l, const Tw& T)
{
    float xr[8], xi[8];
    // ---- stage 0 (s=1): twiddle W^{l*m} ----
#pragma unroll
    for (int q = 0; q < 8; ++q) { float2 v = wk[swz(l + 64*q)]; xr[q]=v.x; xi[q]=v.y; }
    WAVE_FENCE();
    dft8<INV>(xr, xi);
#pragma unroll
    for (int m = 1; m < 8; ++m) {
        float wr = T.t0r[m-1], wi = INV ? -T.t0i[m-1] : T.t0i[m-1];
        float nr = xr[m]*wr - xi[m]*wi, ni = xr[m]*wi + xi[m]*wr;
        xr[m]=nr; xi[m]=ni;
    }
#pragma unroll
    for (int m = 0; m < 8; ++m) wk[swz(8*l + m)] = make_float2(xr[m], xi[m]);
    WAVE_FENCE();
    // ---- stage 1 (s=8): twiddle W^{8*(l>>3)*m} ----
#pragma unroll
    for (int q = 0; q < 8; ++q) { float2 v = wk[swz(l + 64*q)]; xr[q]=v.x; xi[q]=v.y; }
    WAVE_FENCE();
    dft8<INV>(xr, xi);
#pragma unroll
    for (int m = 1; m < 8; ++m) {
        float wr = T.t1r[m-1], wi = INV ? -T.t1i[m-1] : T.t1i[m-1];
        float nr = xr[m]*wr - xi[m]*wi, ni = xr[m]*wi + xi[m]*wr;
        xr[m]=nr; xi[m]=ni;
    }
    {
        const int base = 64*(l>>3) + (l&7);
#pragma unroll
        for (int m = 0; m < 8; ++m) wk[swz(base + 8*m)] = make_float2(xr[m], xi[m]);
    }
    WAVE_FENCE();
    // ---- stage 2 (s=64): no twiddle ----
#pragma unroll
    for (int q = 0; q < 8; ++q) { float2 v = wk[swz(l + 64*q)]; xr[q]=v.x; xi[q]=v.y; }
    WAVE_FENCE();
    dft8<INV>(xr, xi);
#pragma unroll
    for (int m = 0; m < 8; ++m) wk[swz(l + 64*m)] = make_float2(xr[m], xi[m]);
    WAVE_FENCE();
}

// ---------------- weight spectra precompute: one wave per weight block ----------------
// wsp (float2): blocks 0..43 = rfft(wg)/512 (idx q*4+p), 44..87 = rfft(wu)/512,
// 88..131 = rfft(wd)/512 (idx p*11+q). 257 entries per block.
__global__ __launch_bounds__(64) void wf_prep(const float* __restrict__ wg,
                                              const float* __restrict__ wu,
                                              const float* __restrict__ wd,
                                              float2* __restrict__ wsp)
{
    __shared__ float2 wk[512];
    const int t = threadIdx.x;
    Tw T; make_tw(t, T);
    const int b = blockIdx.x;      // 0..131
    const float* src = (b < 44) ? (wg + (size_t)b * 512)
                     : (b < 88) ? (wu + (size_t)(b - 44) * 512)
                                : (wd + (size_t)(b - 88) * 512);
    float2* dst = wsp + (size_t)b * 257;

#pragma unroll
    for (int i = 0; i < 8; ++i) { int n = t + 64*i; wk[swz(n)] = make_float2(src[n], 0.f); }
    WAVE_FENCE();
    fft512_r8<false>(wk, t, T);
    const float sc = 1.0f / 512.0f;   // fold irfft 1/N into the weight spectrum
#pragma unroll
    for (int i = 0; i < 5; ++i) {
        int k = t + 64*i;
        if (k <= 256) { float2 z = wk[swz(k)]; dst[k] = make_float2(sc*z.x, sc*z.y); }
    }
}

// ---------------- fused FFN: one 256-thread block per row ----------------
__global__ __launch_bounds__(256) void bcffn(const float* __restrict__ x,
                                             const float2* __restrict__ wsp,
                                             float* __restrict__ out)
{
    __shared__ float2 sWork[4 * 512];   // 16 KB    per-wave FFT buffers (swizzled)
    __shared__ float2 sXf[4][257];      //  8.2 KB  X spectra (half, Hermitian)
    __shared__ float2 sHf[4][257];      //  8.2 KB  rotating H spectra (one round)
                                        // 32.1 KB -> 4 blocks/CU

    const int tid = threadIdx.x;
    const int t = tid & 63, w = tid >> 6;
    const size_t row = blockIdx.x;

    Tw T; make_tw(t, T);

    const float2* Wg = wsp;
    const float2* Wu = wsp + 44 * 257;
    const float2* Wd = wsp + 88 * 257;

    float2* wk = sWork + (w << 9);

    // per-wave register Z accumulator for output block p=w: Z[k=t+64u]
    float Zr[5] = {0.f, 0.f, 0.f, 0.f, 0.f};
    float Zi[5] = {0.f, 0.f, 0.f, 0.f, 0.f};

    // ---- P1: wave w: FFT of x block w (imag = 0) ----
    {
        const float4* x4 = (const float4*)(x + row * 2048 + (size_t)w * 512);
#pragma unroll
        for (int u = 0; u < 2; ++u) {
            int e = t + 64*u;
            float4 a = x4[e];
            int n = 4*e;
            wk[swz(n+0)] = make_float2(a.x, 0.f);
            wk[swz(n+1)] = make_float2(a.y, 0.f);
            wk[swz(n+2)] = make_float2(a.z, 0.f);
            wk[swz(n+3)] = make_float2(a.w, 0.f);
        }
    }
    WAVE_FENCE();
    fft512_r8<false>(wk, t, T);
#pragma unroll
    for (int u = 0; u < 5; ++u) {
        int k = t + 64*u;
        if (k <= 256) sXf[w][k] = wk[swz(k)];
    }
    __syncthreads();

    // ---- P2: 3 rounds of 4 q's. Per round: wave w computes Hf[q=4r+w] into
    //      sHf[w]; barrier; every wave accumulates the round's q-terms into
    //      its register Z (output block p=w); barrier. ----
#pragma unroll 1
    for (int r = 0; r < 3; ++r) {
        const int q = r * 4 + w;
        if (q < 11) {
#pragma unroll
            for (int u = 0; u < 5; ++u) {
                int k = t + 64*u;
                if (k <= 256) {
                    float gr=0.f, gi=0.f, ur_=0.f, ui_=0.f;
#pragma unroll
                    for (int p = 0; p < 4; ++p) {
                        float2 X = sXf[p][k];
                        float2 a = Wg[(q*4 + p)*257 + k];
                        float2 b = Wu[(q*4 + p)*257 + k];
                        gr  += X.x*a.x - X.y*a.y;  gi  += X.x*a.y + X.y*a.x;
                        ur_ += X.x*b.x - X.y*b.y;  ui_ += X.x*b.y + X.y*b.x;
                    }
                    // packed spectrum Z = G + i*U  (z = g + i*u in time domain)
                    wk[swz(k)] = make_float2(gr - ui_, gi + ur_);
                    if (k != 0 && k != 256)
                        wk[swz(512 - k)] = make_float2(gr + ui_, ur_ - gi);
                }
            }
            WAVE_FENCE();
            fft512_r8<true>(wk, t, T);     // unscaled inverse; 1/512 lives in W
#pragma unroll
            for (int u = 0; u < 8; ++u) {
                int n = t + 64*u;
                float2 v = wk[swz(n)];
                float h = v.x * v.y / (1.f + __expf(-v.x));   // silu(g)*u
                wk[swz(n)] = make_float2(h, 0.f);             // same-lane RMW
            }
            WAVE_FENCE();
            fft512_r8<false>(wk, t, T);
#pragma unroll
            for (int u = 0; u < 5; ++u) {
                int k = t + 64*u;
                if (k <= 256) sHf[w][k] = wk[swz(k)];
            }
        }
        __syncthreads();   // round's Hf visible to all waves
        {
            const int nj = (r < 2) ? 4 : 3;
#pragma unroll
            for (int j = 0; j < 4; ++j) {
                if (j < nj) {
                    const int qq = r * 4 + j;
                    const float2* wdq = Wd + (size_t)(w*11 + qq) * 257;
#pragma unroll
                    for (int u = 0; u < 5; ++u) {
                        int k = t + 64*u;
                        if (k <= 256) {
                            float2 H = sHf[j][k];
                            float2 d = wdq[k];
                            Zr[u] += H.x*d.x - H.y*d.y;
                            Zi[u] += H.x*d.y + H.y*d.x;
                        }
                    }
                }
            }
        }
        __syncthreads();   // reads done before next round overwrites sHf
    }

    // ---- P3: wave w = output block p=w: iFFT of register Z ----
#pragma unroll
    for (int u = 0; u < 5; ++u) {
        int k = t + 64*u;
        if (k <= 256) {
            wk[swz(k)] = make_float2(Zr[u], Zi[u]);
            if (k != 0 && k != 256)
                wk[swz(512 - k)] = make_float2(Zr[u], -Zi[u]);
        }
    }
    WAVE_FENCE();
    fft512_r8<true>(wk, t, T);
    {
        float4* o4 = (float4*)(out + row * 2048 + (size_t)w * 512);
#pragma unroll
        for (int u = 0; u < 2; ++u) {
            int e = t + 64*u;
            int n = 4*e;
            o4[e] = make_float4(wk[swz(n)].x, wk[swz(n+1)].x,
                                wk[swz(n+2)].x, wk[swz(n+3)].x);
        }
    }
}

extern "C" void kernel_launch(void* const* d_in, const int* in_sizes, int n_in,
                              void* d_out, int out_size, void* d_ws, size_t ws_size,
                              hipStream_t stream)
{
    (void)n_in; (void)out_size; (void)ws_size;
    const float* x  = (const float*)d_in[0];
    const float* wg = (const float*)d_in[1];
    const float* wu = (const float*)d_in[2];
    const float* wd = (const float*)d_in[3];
    float2* wsp = (float2*)d_ws;          // 132*257 float2 = 271 KB used
    float*  out = (float*)d_out;

    const int rows = in_sizes[0] / 2048;  // 16384

    wf_prep<<<132, 64, 0, stream>>>(wg, wu, wd, wsp);
    bcffn<<<rows, 256, 0, stream>>>(x, wsp, out);
}

// Round 6
// 579.628 us; speedup vs baseline: 3.8120x; 1.1531x over previous
//
#include <hip/hip_runtime.h>
#include <math.h>

// Block-circulant SwiGLU FFN via per-wave radix-8 FFT-512 (CirCNN style).
// d_model=2048 (p=4 blocks), d_ff=5632 (q=11 blocks), BLOCK=512.
// Round-6: R3 verified base + real-signal PACKING within one row:
//   P1: 2 packed FFTs (x-block pairs) instead of 4 real FFTs
//   P2: forward FFT of h packed across q-pairs {w, w+4}; q=8,9,10 unpacked
//   P3: 2 packed inverse FFTs (Z-block pairs) instead of 4
// FFTs/row: 30 -> 22. Pack/unpack algebra hardware-verified in R2.

#define WAVE_FENCE() do { asm volatile("s_waitcnt lgkmcnt(0)" ::: "memory"); \
                          __builtin_amdgcn_sched_barrier(0); } while (0)

// LDS element-index swizzle: every access pattern used here (stage reads
// l+64q, writes 8l+m / 64a+b+8m / l+64m, einsum k and 512-k) is GF(2)-linear
// rank-4 in lane bits -> uniform 4 lanes per bank pair (b64 minimum).
__device__ __forceinline__ int swz(int n) { return n ^ ((n >> 3) & 15); }

struct Tw { float t0r[7], t0i[7], t1r[7], t1i[7]; };

// Per-lane register twiddles: stage0 W512^{l*m}, stage1 W512^{8*(l>>3)*m}.
__device__ __forceinline__ void make_tw(int l, Tw& T)
{
    float c0, s0;
    __sincosf(-6.283185307179586f * (float)l * (1.0f/512.0f), &s0, &c0);
    float pr = c0, pi = s0;
    T.t0r[0] = pr; T.t0i[0] = pi;
#pragma unroll
    for (int m = 1; m < 7; ++m) {
        float nr = pr*c0 - pi*s0, ni = pr*s0 + pi*c0;
        pr = nr; pi = ni;
        T.t0r[m] = pr; T.t0i[m] = pi;
    }
    float c1, s1;
    __sincosf(-6.283185307179586f * (float)(l >> 3) * (1.0f/64.0f), &s1, &c1);
    pr = c1; pi = s1;
    T.t1r[0] = pr; T.t1i[0] = pi;
#pragma unroll
    for (int m = 1; m < 7; ++m) {
        float nr = pr*c1 - pi*s1, ni = pr*s1 + pi*c1;
        pr = nr; pi = ni;
        T.t1r[m] = pr; T.t1i[m] = pi;
    }
}

// 8-point DFT (DIF): A_m = sum_q a_q w8^{qm}, w8 = e^{-2pi i/8} (conj if INV).
template<bool INV>
__device__ __forceinline__ void dft8(float xr[8], float xi[8])
{
    const float C = 0.70710678118654752f;
    float tr[4], ti[4], ur[4], ui[4];
#pragma unroll
    for (int q = 0; q < 4; ++q) {
        tr[q] = xr[q] + xr[q+4];  ti[q] = xi[q] + xi[q+4];
        ur[q] = xr[q] - xr[q+4];  ui[q] = xi[q] - xi[q+4];
    }
    {
        float xx = ur[1], yy = ui[1];
        if (!INV) { ur[1] = C*(xx+yy); ui[1] = C*(yy-xx); }
        else      { ur[1] = C*(xx-yy); ui[1] = C*(xx+yy); }
    }
    {
        float xx = ur[2], yy = ui[2];
        if (!INV) { ur[2] = yy;  ui[2] = -xx; }
        else      { ur[2] = -yy; ui[2] = xx; }
    }
    {
        float xx = ur[3], yy = ui[3];
        if (!INV) { ur[3] = C*(yy-xx);  ui[3] = -C*(xx+yy); }
        else      { ur[3] = -C*(xx+yy); ui[3] = C*(xx-yy); }
    }
    {
        float s0r=tr[0]+tr[2], s0i=ti[0]+ti[2];
        float d0r=tr[0]-tr[2], d0i=ti[0]-ti[2];
        float s1r=tr[1]+tr[3], s1i=ti[1]+ti[3];
        float e1r=tr[1]-tr[3], e1i=ti[1]-ti[3];
        float d1r, d1i;
        if (!INV) { d1r = e1i;  d1i = -e1r; } else { d1r = -e1i; d1i = e1r; }
        xr[0]=s0r+s1r; xi[0]=s0i+s1i;
        xr[2]=d0r+d1r; xi[2]=d0i+d1i;
        xr[4]=s0r-s1r; xi[4]=s0i-s1i;
        xr[6]=d0r-d1r; xi[6]=d0i-d1i;
    }
    {
        float s0r=ur[0]+ur[2], s0i=ui[0]+ui[2];
        float d0r=ur[0]-ur[2], d0i=ui[0]-ui[2];
        float s1r=ur[1]+ur[3], s1i=ui[1]+ui[3];
        float e1r=ur[1]-ur[3], e1i=ui[1]-ui[3];
        float d1r, d1i;
        if (!INV) { d1r = e1i;  d1i = -e1r; } else { d1r = -e1i; d1i = e1r; }
        xr[1]=s0r+s1r; xi[1]=s0i+s1i;
        xr[3]=d0r+d1r; xi[3]=d0i+d1i;
        xr[5]=s0r-s1r; xi[5]=s0i-s1i;
        xr[7]=d0r-d1r; xi[7]=d0i-d1i;
    }
}

// In-place radix-8 Stockham FFT-512 on a wave-private (swizzled) LDS buffer.
// Natural-order in/out; forward = e^{-i}, INV = conjugated (unscaled inverse).
template<bool INV>
__device__ __forceinline__ void fft512_r8(float2* wk, int l, const Tw& T)
{
    float xr[8], xi[8];
    // ---- stage 0 (s=1): twiddle W^{l*m} ----
#pragma unroll
    for (int q = 0; q < 8; ++q) { float2 v = wk[swz(l + 64*q)]; xr[q]=v.x; xi[q]=v.y; }
    WAVE_FENCE();
    dft8<INV>(xr, xi);
#pragma unroll
    for (int m = 1; m < 8; ++m) {
        float wr = T.t0r[m-1], wi = INV ? -T.t0i[m-1] : T.t0i[m-1];
        float nr = xr[m]*wr - xi[m]*wi, ni = xr[m]*wi + xi[m]*wr;
        xr[m]=nr; xi[m]=ni;
    }
#pragma unroll
    for (int m = 0; m < 8; ++m) wk[swz(8*l + m)] = make_float2(xr[m], xi[m]);
    WAVE_FENCE();
    // ---- stage 1 (s=8): twiddle W^{8*(l>>3)*m} ----
#pragma unroll
    for (int q = 0; q < 8; ++q) { float2 v = wk[swz(l + 64*q)]; xr[q]=v.x; xi[q]=v.y; }
    WAVE_FENCE();
    dft8<INV>(xr, xi);
#pragma unroll
    for (int m = 1; m < 8; ++m) {
        float wr = T.t1r[m-1], wi = INV ? -T.t1i[m-1] : T.t1i[m-1];
        float nr = xr[m]*wr - xi[m]*wi, ni = xr[m]*wi + xi[m]*wr;
        xr[m]=nr; xi[m]=ni;
    }
    {
        const int base = 64*(l>>3) + (l&7);
#pragma unroll
        for (int m = 0; m < 8; ++m) wk[swz(base + 8*m)] = make_float2(xr[m], xi[m]);
    }
    WAVE_FENCE();
    // ---- stage 2 (s=64): no twiddle ----
#pragma unroll
    for (int q = 0; q < 8; ++q) { float2 v = wk[swz(l + 64*q)]; xr[q]=v.x; xi[q]=v.y; }
    WAVE_FENCE();
    dft8<INV>(xr, xi);
#pragma unroll
    for (int m = 0; m < 8; ++m) wk[swz(l + 64*m)] = make_float2(xr[m], xi[m]);
    WAVE_FENCE();
}

// ---------------- weight spectra precompute: one wave per weight block ----------------
// wsp (float2): blocks 0..43 = rfft(wg)/512 (idx q*4+p), 44..87 = rfft(wu)/512,
// 88..131 = rfft(wd)/512 (idx p*11+q). 257 entries per block.
__global__ __launch_bounds__(64) void wf_prep(const float* __restrict__ wg,
                                              const float* __restrict__ wu,
                                              const float* __restrict__ wd,
                                              float2* __restrict__ wsp)
{
    __shared__ float2 wk[512];
    const int t = threadIdx.x;
    Tw T; make_tw(t, T);
    const int b = blockIdx.x;      // 0..131
    const float* src = (b < 44) ? (wg + (size_t)b * 512)
                     : (b < 88) ? (wu + (size_t)(b - 44) * 512)
                                : (wd + (size_t)(b - 88) * 512);
    float2* dst = wsp + (size_t)b * 257;

#pragma unroll
    for (int i = 0; i < 8; ++i) { int n = t + 64*i; wk[swz(n)] = make_float2(src[n], 0.f); }
    WAVE_FENCE();
    fft512_r8<false>(wk, t, T);
    const float sc = 1.0f / 512.0f;   // fold irfft 1/N into the weight spectrum
#pragma unroll
    for (int i = 0; i < 5; ++i) {
        int k = t + 64*i;
        if (k <= 256) { float2 z = wk[swz(k)]; dst[k] = make_float2(sc*z.x, sc*z.y); }
    }
}

// ---------------- fused FFN: one 256-thread block per row ----------------
__global__ __launch_bounds__(256) void bcffn(const float* __restrict__ x,
                                             const float2* __restrict__ wsp,
                                             float* __restrict__ out)
{
    __shared__ float2 sWork[4 * 512];   // 16 KB    per-wave FFT buffers (swizzled)
    __shared__ float2 sXf[4][257];      //  8.2 KB  X spectra; reused as Z scratch in P3
    __shared__ float2 sHf[11][257];     // 22.6 KB  H spectra
                                        // ~46.9 KB -> 3 blocks/CU

    const int tid = threadIdx.x;
    const int t = tid & 63, w = tid >> 6;
    const size_t row = blockIdx.x;

    Tw T; make_tw(t, T);

    const float2* Wg = wsp;
    const float2* Wu = wsp + 44 * 257;
    const float2* Wd = wsp + 88 * 257;

    float2* wk = sWork + (w << 9);

    // ---- P1: waves 0,1: packed FFT of (x block 2w) + i*(x block 2w+1) ----
    if (w < 2) {
        const float4* xa = (const float4*)(x + row * 2048 + (size_t)(2*w)   * 512);
        const float4* xb = (const float4*)(x + row * 2048 + (size_t)(2*w+1) * 512);
#pragma unroll
        for (int u = 0; u < 2; ++u) {
            int e = t + 64*u;
            float4 a = xa[e], b = xb[e];
            int n = 4*e;
            wk[swz(n+0)] = make_float2(a.x, b.x);
            wk[swz(n+1)] = make_float2(a.y, b.y);
            wk[swz(n+2)] = make_float2(a.z, b.z);
            wk[swz(n+3)] = make_float2(a.w, b.w);
        }
        WAVE_FENCE();
        fft512_r8<false>(wk, t, T);
#pragma unroll
        for (int u = 0; u < 5; ++u) {
            int k = t + 64*u;
            if (k <= 256) {
                float2 z = wk[swz(k)], m = wk[swz((512 - k) & 511)];
                sXf[2*w][k]   = make_float2(0.5f*(z.x + m.x), 0.5f*(z.y - m.y));
                sXf[2*w+1][k] = make_float2(0.5f*(z.y + m.y), 0.5f*(m.x - z.x));
            }
        }
    }
    __syncthreads();

    // einsum for block-row q: packed spectrum Z = G + i*U into wk (all 512)
    auto einsum_gu = [&](int q) {
#pragma unroll
        for (int u = 0; u < 5; ++u) {
            int k = t + 64*u;
            if (k <= 256) {
                float gr=0.f, gi=0.f, ur_=0.f, ui_=0.f;
#pragma unroll
                for (int p = 0; p < 4; ++p) {
                    float2 X = sXf[p][k];
                    float2 a = Wg[(q*4 + p)*257 + k];
                    float2 b = Wu[(q*4 + p)*257 + k];
                    gr  += X.x*a.x - X.y*a.y;  gi  += X.x*a.y + X.y*a.x;
                    ur_ += X.x*b.x - X.y*b.y;  ui_ += X.x*b.y + X.y*b.x;
                }
                wk[swz(k)] = make_float2(gr - ui_, gi + ur_);
                if (k != 0 && k != 256)
                    wk[swz(512 - k)] = make_float2(gr + ui_, ur_ - gi);
            }
        }
    };

    // ---- P2: q-pair (qa=w, qb=w+4) with packed forward FFT; leftover qc=w+8 ----
    {
        const int qa = w, qb = w + 4;
        float ha[8];

        einsum_gu(qa);
        WAVE_FENCE();
        fft512_r8<true>(wk, t, T);            // z = g + i*u for qa
#pragma unroll
        for (int u = 0; u < 8; ++u) {
            float2 v = wk[swz(t + 64*u)];
            ha[u] = v.x * v.y / (1.f + __expf(-v.x));      // h(qa) -> regs
        }
        WAVE_FENCE();                          // ha reads drained before qb writes

        einsum_gu(qb);
        WAVE_FENCE();
        fft512_r8<true>(wk, t, T);            // z = g + i*u for qb
#pragma unroll
        for (int u = 0; u < 8; ++u) {
            int n = t + 64*u;
            float2 v = wk[swz(n)];
            float hb = v.x * v.y / (1.f + __expf(-v.x));
            wk[swz(n)] = make_float2(ha[u], hb);           // pack h(qa)+i*h(qb)
        }
        WAVE_FENCE();
        fft512_r8<false>(wk, t, T);           // one FFT -> both H spectra
#pragma unroll
        for (int u = 0; u < 5; ++u) {
            int k = t + 64*u;
            if (k <= 256) {
                float2 z = wk[swz(k)], m = wk[swz((512 - k) & 511)];
                sHf[qa][k] = make_float2(0.5f*(z.x + m.x), 0.5f*(z.y - m.y));
                sHf[qb][k] = make_float2(0.5f*(z.y + m.y), 0.5f*(m.x - z.x));
            }
        }
        WAVE_FENCE();                          // unpack reads drained before qc writes

        if (w < 3) {
            const int qc = w + 8;
            einsum_gu(qc);
            WAVE_FENCE();
            fft512_r8<true>(wk, t, T);
#pragma unroll
            for (int u = 0; u < 8; ++u) {
                int n = t + 64*u;
                float2 v = wk[swz(n)];
                wk[swz(n)] = make_float2(v.x * v.y / (1.f + __expf(-v.x)), 0.f);
            }
            WAVE_FENCE();
            fft512_r8<false>(wk, t, T);
#pragma unroll
            for (int u = 0; u < 5; ++u) {
                int k = t + 64*u;
                if (k <= 256) sHf[qc][k] = wk[swz(k)];
            }
        }
    }
    __syncthreads();

    // ---- P3: all waves einsum Z_{p=w}; waves 2,3 publish to scratch;
    //      waves 0,1 pack (Z_w + i*Z_{w+2}) -> one iFFT -> two output blocks ----
    float Zr[5] = {0.f,0.f,0.f,0.f,0.f};
    float Zi[5] = {0.f,0.f,0.f,0.f,0.f};
#pragma unroll
    for (int u = 0; u < 5; ++u) {
        int k = t + 64*u;
        if (k <= 256) {
            float zr = 0.f, zi = 0.f;
#pragma unroll
            for (int q = 0; q < 11; ++q) {
                float2 H = sHf[q][k];
                float2 d = Wd[(w*11 + q)*257 + k];
                zr += H.x*d.x - H.y*d.y;
                zi += H.x*d.y + H.y*d.x;
            }
            Zr[u] = zr; Zi[u] = zi;
        }
    }
    if (w >= 2) {       // publish Z_p2 -> sXf[0], Z_p3 -> sXf[1] (sXf reads all done)
#pragma unroll
        for (int u = 0; u < 5; ++u) {
            int k = t + 64*u;
            if (k <= 256) sXf[w-2][k] = make_float2(Zr[u], Zi[u]);
        }
    }
    __syncthreads();
    if (w < 2) {
#pragma unroll
        for (int u = 0; u < 5; ++u) {
            int k = t + 64*u;
            if (k <= 256) {
                float2 zb = sXf[w][k];          // partner spectrum Z_{w+2}
                wk[swz(k)] = make_float2(Zr[u] - zb.y, Zi[u] + zb.x);
                if (k != 0 && k != 256)
                    wk[swz(512 - k)] = make_float2(Zr[u] + zb.y, zb.x - Zi[u]);
            }
        }
        WAVE_FENCE();
        fft512_r8<true>(wk, t, T);
        float4* oa = (float4*)(out + row * 2048 + (size_t)w       * 512);
        float4* ob = (float4*)(out + row * 2048 + (size_t)(w + 2) * 512);
#pragma unroll
        for (int u = 0; u < 2; ++u) {
            int e = t + 64*u, n = 4*e;
            float2 v0 = wk[swz(n)],   v1 = wk[swz(n+1)];
            float2 v2 = wk[swz(n+2)], v3 = wk[swz(n+3)];
            oa[e] = make_float4(v0.x, v1.x, v2.x, v3.x);
            ob[e] = make_float4(v0.y, v1.y, v2.y, v3.y);
        }
    }
}

extern "C" void kernel_launch(void* const* d_in, const int* in_sizes, int n_in,
                              void* d_out, int out_size, void* d_ws, size_t ws_size,
                              hipStream_t stream)
{
    (void)n_in; (void)out_size; (void)ws_size;
    const float* x  = (const float*)d_in[0];
    const float* wg = (const float*)d_in[1];
    const float* wu = (const float*)d_in[2];
    const float* wd = (const float*)d_in[3];
    float2* wsp = (float2*)d_ws;          // 132*257 float2 = 271 KB used
    float*  out = (float*)d_out;

    const int rows = in_sizes[0] / 2048;  // 16384

    wf_prep<<<132, 64, 0, stream>>>(wg, wu, wd, wsp);
    bcffn<<<rows, 256, 0, stream>>>(x, wsp, out);
}

// Round 7
// 549.604 us; speedup vs baseline: 4.0203x; 1.0546x over previous
//
#include <hip/hip_runtime.h>
#include <math.h>

// Block-circulant SwiGLU FFN via per-wave radix-8 FFT-512 (CirCNN style).
// d_model=2048 (p=4 blocks), d_ff=5632 (q=11 blocks), BLOCK=512.
// Round-7: R6 structure, ONE change: all explicit WAVE_FENCEs removed.
// Safety: every FFT hazard is same-wave on a wave-private LDS buffer; the
// DS pipe processes one wave's LDS ops in order, the compiler preserves
// aliasing read/write order and inserts minimal lgkmcnt(N) for data returns.
// Fenceless FFT already hardware-verified in R4 (bit-identical absmax).

// LDS element-index swizzle: every access pattern used here (stage reads
// l+64q, writes 8l+m / 64a+b+8m / l+64m, einsum k and 512-k) is GF(2)-linear
// rank-4 in lane bits -> uniform 4 lanes per bank pair (b64 minimum).
__device__ __forceinline__ int swz(int n) { return n ^ ((n >> 3) & 15); }

struct Tw { float t0r[7], t0i[7], t1r[7], t1i[7]; };

// Per-lane register twiddles: stage0 W512^{l*m}, stage1 W512^{8*(l>>3)*m}.
__device__ __forceinline__ void make_tw(int l, Tw& T)
{
    float c0, s0;
    __sincosf(-6.283185307179586f * (float)l * (1.0f/512.0f), &s0, &c0);
    float pr = c0, pi = s0;
    T.t0r[0] = pr; T.t0i[0] = pi;
#pragma unroll
    for (int m = 1; m < 7; ++m) {
        float nr = pr*c0 - pi*s0, ni = pr*s0 + pi*c0;
        pr = nr; pi = ni;
        T.t0r[m] = pr; T.t0i[m] = pi;
    }
    float c1, s1;
    __sincosf(-6.283185307179586f * (float)(l >> 3) * (1.0f/64.0f), &s1, &c1);
    pr = c1; pi = s1;
    T.t1r[0] = pr; T.t1i[0] = pi;
#pragma unroll
    for (int m = 1; m < 7; ++m) {
        float nr = pr*c1 - pi*s1, ni = pr*s1 + pi*c1;
        pr = nr; pi = ni;
        T.t1r[m] = pr; T.t1i[m] = pi;
    }
}

// 8-point DFT (DIF): A_m = sum_q a_q w8^{qm}, w8 = e^{-2pi i/8} (conj if INV).
template<bool INV>
__device__ __forceinline__ void dft8(float xr[8], float xi[8])
{
    const float C = 0.70710678118654752f;
    float tr[4], ti[4], ur[4], ui[4];
#pragma unroll
    for (int q = 0; q < 4; ++q) {
        tr[q] = xr[q] + xr[q+4];  ti[q] = xi[q] + xi[q+4];
        ur[q] = xr[q] - xr[q+4];  ui[q] = xi[q] - xi[q+4];
    }
    {
        float xx = ur[1], yy = ui[1];
        if (!INV) { ur[1] = C*(xx+yy); ui[1] = C*(yy-xx); }
        else      { ur[1] = C*(xx-yy); ui[1] = C*(xx+yy); }
    }
    {
        float xx = ur[2], yy = ui[2];
        if (!INV) { ur[2] = yy;  ui[2] = -xx; }
        else      { ur[2] = -yy; ui[2] = xx; }
    }
    {
        float xx = ur[3], yy = ui[3];
        if (!INV) { ur[3] = C*(yy-xx);  ui[3] = -C*(xx+yy); }
        else      { ur[3] = -C*(xx+yy); ui[3] = C*(xx-yy); }
    }
    {
        float s0r=tr[0]+tr[2], s0i=ti[0]+ti[2];
        float d0r=tr[0]-tr[2], d0i=ti[0]-ti[2];
        float s1r=tr[1]+tr[3], s1i=ti[1]+ti[3];
        float e1r=tr[1]-tr[3], e1i=ti[1]-ti[3];
        float d1r, d1i;
        if (!INV) { d1r = e1i;  d1i = -e1r; } else { d1r = -e1i; d1i = e1r; }
        xr[0]=s0r+s1r; xi[0]=s0i+s1i;
        xr[2]=d0r+d1r; xi[2]=d0i+d1i;
        xr[4]=s0r-s1r; xi[4]=s0i-s1i;
        xr[6]=d0r-d1r; xi[6]=d0i-d1i;
    }
    {
        float s0r=ur[0]+ur[2], s0i=ui[0]+ui[2];
        float d0r=ur[0]-ur[2], d0i=ui[0]-ui[2];
        float s1r=ur[1]+ur[3], s1i=ui[1]+ui[3];
        float e1r=ur[1]-ur[3], e1i=ui[1]-ui[3];
        float d1r, d1i;
        if (!INV) { d1r = e1i;  d1i = -e1r; } else { d1r = -e1i; d1i = e1r; }
        xr[1]=s0r+s1r; xi[1]=s0i+s1i;
        xr[3]=d0r+d1r; xi[3]=d0i+d1i;
        xr[5]=s0r-s1r; xi[5]=s0i-s1i;
        xr[7]=d0r-d1r; xi[7]=d0i-d1i;
    }
}

// In-place radix-8 Stockham FFT-512 on a wave-private (swizzled) LDS buffer.
// Natural-order in/out; forward = e^{-i}, INV = conjugated (unscaled inverse).
// No explicit fences (see header comment).
template<bool INV>
__device__ __forceinline__ void fft512_r8(float2* wk, int l, const Tw& T)
{
    float xr[8], xi[8];
    // ---- stage 0 (s=1): twiddle W^{l*m} ----
#pragma unroll
    for (int q = 0; q < 8; ++q) { float2 v = wk[swz(l + 64*q)]; xr[q]=v.x; xi[q]=v.y; }
    dft8<INV>(xr, xi);
#pragma unroll
    for (int m = 1; m < 8; ++m) {
        float wr = T.t0r[m-1], wi = INV ? -T.t0i[m-1] : T.t0i[m-1];
        float nr = xr[m]*wr - xi[m]*wi, ni = xr[m]*wi + xi[m]*wr;
        xr[m]=nr; xi[m]=ni;
    }
#pragma unroll
    for (int m = 0; m < 8; ++m) wk[swz(8*l + m)] = make_float2(xr[m], xi[m]);
    // ---- stage 1 (s=8): twiddle W^{8*(l>>3)*m} ----
#pragma unroll
    for (int q = 0; q < 8; ++q) { float2 v = wk[swz(l + 64*q)]; xr[q]=v.x; xi[q]=v.y; }
    dft8<INV>(xr, xi);
#pragma unroll
    for (int m = 1; m < 8; ++m) {
        float wr = T.t1r[m-1], wi = INV ? -T.t1i[m-1] : T.t1i[m-1];
        float nr = xr[m]*wr - xi[m]*wi, ni = xr[m]*wi + xi[m]*wr;
        xr[m]=nr; xi[m]=ni;
    }
    {
        const int base = 64*(l>>3) + (l&7);
#pragma unroll
        for (int m = 0; m < 8; ++m) wk[swz(base + 8*m)] = make_float2(xr[m], xi[m]);
    }
    // ---- stage 2 (s=64): no twiddle ----
#pragma unroll
    for (int q = 0; q < 8; ++q) { float2 v = wk[swz(l + 64*q)]; xr[q]=v.x; xi[q]=v.y; }
    dft8<INV>(xr, xi);
#pragma unroll
    for (int m = 0; m < 8; ++m) wk[swz(l + 64*m)] = make_float2(xr[m], xi[m]);
}

// ---------------- weight spectra precompute: one wave per weight block ----------------
// wsp (float2): blocks 0..43 = rfft(wg)/512 (idx q*4+p), 44..87 = rfft(wu)/512,
// 88..131 = rfft(wd)/512 (idx p*11+q). 257 entries per block.
__global__ __launch_bounds__(64) void wf_prep(const float* __restrict__ wg,
                                              const float* __restrict__ wu,
                                              const float* __restrict__ wd,
                                              float2* __restrict__ wsp)
{
    __shared__ float2 wk[512];
    const int t = threadIdx.x;
    Tw T; make_tw(t, T);
    const int b = blockIdx.x;      // 0..131
    const float* src = (b < 44) ? (wg + (size_t)b * 512)
                     : (b < 88) ? (wu + (size_t)(b - 44) * 512)
                                : (wd + (size_t)(b - 88) * 512);
    float2* dst = wsp + (size_t)b * 257;

#pragma unroll
    for (int i = 0; i < 8; ++i) { int n = t + 64*i; wk[swz(n)] = make_float2(src[n], 0.f); }
    fft512_r8<false>(wk, t, T);
    const float sc = 1.0f / 512.0f;   // fold irfft 1/N into the weight spectrum
#pragma unroll
    for (int i = 0; i < 5; ++i) {
        int k = t + 64*i;
        if (k <= 256) { float2 z = wk[swz(k)]; dst[k] = make_float2(sc*z.x, sc*z.y); }
    }
}

// ---------------- fused FFN: one 256-thread block per row ----------------
__global__ __launch_bounds__(256) void bcffn(const float* __restrict__ x,
                                             const float2* __restrict__ wsp,
                                             float* __restrict__ out)
{
    __shared__ float2 sWork[4 * 512];   // 16 KB    per-wave FFT buffers (swizzled)
    __shared__ float2 sXf[4][257];      //  8.2 KB  X spectra; reused as Z scratch in P3
    __shared__ float2 sHf[11][257];     // 22.6 KB  H spectra
                                        // ~46.9 KB -> 3 blocks/CU

    const int tid = threadIdx.x;
    const int t = tid & 63, w = tid >> 6;
    const size_t row = blockIdx.x;

    Tw T; make_tw(t, T);

    const float2* Wg = wsp;
    const float2* Wu = wsp + 44 * 257;
    const float2* Wd = wsp + 88 * 257;

    float2* wk = sWork + (w << 9);

    // ---- P1: waves 0,1: packed FFT of (x block 2w) + i*(x block 2w+1) ----
    if (w < 2) {
        const float4* xa = (const float4*)(x + row * 2048 + (size_t)(2*w)   * 512);
        const float4* xb = (const float4*)(x + row * 2048 + (size_t)(2*w+1) * 512);
#pragma unroll
        for (int u = 0; u < 2; ++u) {
            int e = t + 64*u;
            float4 a = xa[e], b = xb[e];
            int n = 4*e;
            wk[swz(n+0)] = make_float2(a.x, b.x);
            wk[swz(n+1)] = make_float2(a.y, b.y);
            wk[swz(n+2)] = make_float2(a.z, b.z);
            wk[swz(n+3)] = make_float2(a.w, b.w);
        }
        fft512_r8<false>(wk, t, T);
#pragma unroll
        for (int u = 0; u < 5; ++u) {
            int k = t + 64*u;
            if (k <= 256) {
                float2 z = wk[swz(k)], m = wk[swz((512 - k) & 511)];
                sXf[2*w][k]   = make_float2(0.5f*(z.x + m.x), 0.5f*(z.y - m.y));
                sXf[2*w+1][k] = make_float2(0.5f*(z.y + m.y), 0.5f*(m.x - z.x));
            }
        }
    }
    __syncthreads();

    // einsum for block-row q: packed spectrum Z = G + i*U into wk (all 512)
    auto einsum_gu = [&](int q) {
#pragma unroll
        for (int u = 0; u < 5; ++u) {
            int k = t + 64*u;
            if (k <= 256) {
                float gr=0.f, gi=0.f, ur_=0.f, ui_=0.f;
#pragma unroll
                for (int p = 0; p < 4; ++p) {
                    float2 X = sXf[p][k];
                    float2 a = Wg[(q*4 + p)*257 + k];
                    float2 b = Wu[(q*4 + p)*257 + k];
                    gr  += X.x*a.x - X.y*a.y;  gi  += X.x*a.y + X.y*a.x;
                    ur_ += X.x*b.x - X.y*b.y;  ui_ += X.x*b.y + X.y*b.x;
                }
                wk[swz(k)] = make_float2(gr - ui_, gi + ur_);
                if (k != 0 && k != 256)
                    wk[swz(512 - k)] = make_float2(gr + ui_, ur_ - gi);
            }
        }
    };

    // ---- P2: q-pair (qa=w, qb=w+4) with packed forward FFT; leftover qc=w+8 ----
    {
        const int qa = w, qb = w + 4;
        float ha[8];

        einsum_gu(qa);
        fft512_r8<true>(wk, t, T);            // z = g + i*u for qa
#pragma unroll
        for (int u = 0; u < 8; ++u) {
            float2 v = wk[swz(t + 64*u)];
            ha[u] = v.x * v.y / (1.f + __expf(-v.x));      // h(qa) -> regs
        }

        einsum_gu(qb);
        fft512_r8<true>(wk, t, T);            // z = g + i*u for qb
#pragma unroll
        for (int u = 0; u < 8; ++u) {
            int n = t + 64*u;
            float2 v = wk[swz(n)];
            float hb = v.x * v.y / (1.f + __expf(-v.x));
            wk[swz(n)] = make_float2(ha[u], hb);           // pack h(qa)+i*h(qb)
        }
        fft512_r8<false>(wk, t, T);           // one FFT -> both H spectra
#pragma unroll
        for (int u = 0; u < 5; ++u) {
            int k = t + 64*u;
            if (k <= 256) {
                float2 z = wk[swz(k)], m = wk[swz((512 - k) & 511)];
                sHf[qa][k] = make_float2(0.5f*(z.x + m.x), 0.5f*(z.y - m.y));
                sHf[qb][k] = make_float2(0.5f*(z.y + m.y), 0.5f*(m.x - z.x));
            }
        }

        if (w < 3) {
            const int qc = w + 8;
            einsum_gu(qc);
            fft512_r8<true>(wk, t, T);
#pragma unroll
            for (int u = 0; u < 8; ++u) {
                int n = t + 64*u;
                float2 v = wk[swz(n)];
                wk[swz(n)] = make_float2(v.x * v.y / (1.f + __expf(-v.x)), 0.f);
            }
            fft512_r8<false>(wk, t, T);
#pragma unroll
            for (int u = 0; u < 5; ++u) {
                int k = t + 64*u;
                if (k <= 256) sHf[qc][k] = wk[swz(k)];
            }
        }
    }
    __syncthreads();

    // ---- P3: all waves einsum Z_{p=w}; waves 2,3 publish to scratch;
    //      waves 0,1 pack (Z_w + i*Z_{w+2}) -> one iFFT -> two output blocks ----
    float Zr[5] = {0.f,0.f,0.f,0.f,0.f};
    float Zi[5] = {0.f,0.f,0.f,0.f,0.f};
#pragma unroll
    for (int u = 0; u < 5; ++u) {
        int k = t + 64*u;
        if (k <= 256) {
            float zr = 0.f, zi = 0.f;
#pragma unroll
            for (int q = 0; q < 11; ++q) {
                float2 H = sHf[q][k];
                float2 d = Wd[(w*11 + q)*257 + k];
                zr += H.x*d.x - H.y*d.y;
                zi += H.x*d.y + H.y*d.x;
            }
            Zr[u] = zr; Zi[u] = zi;
        }
    }
    if (w >= 2) {       // publish Z_p2 -> sXf[0], Z_p3 -> sXf[1] (sXf reads all done)
#pragma unroll
        for (int u = 0; u < 5; ++u) {
            int k = t + 64*u;
            if (k <= 256) sXf[w-2][k] = make_float2(Zr[u], Zi[u]);
        }
    }
    __syncthreads();
    if (w < 2) {
#pragma unroll
        for (int u = 0; u < 5; ++u) {
            int k = t + 64*u;
            if (k <= 256) {
                float2 zb = sXf[w][k];          // partner spectrum Z_{w+2}
                wk[swz(k)] = make_float2(Zr[u] - zb.y, Zi[u] + zb.x);
                if (k != 0 && k != 256)
                    wk[swz(512 - k)] = make_float2(Zr[u] + zb.y, zb.x - Zi[u]);
            }
        }
        fft512_r8<true>(wk, t, T);
        float4* oa = (float4*)(out + row * 2048 + (size_t)w       * 512);
        float4* ob = (float4*)(out + row * 2048 + (size_t)(w + 2) * 512);
#pragma unroll
        for (int u = 0; u < 2; ++u) {
            int e = t + 64*u, n = 4*e;
            float2 v0 = wk[swz(n)],   v1 = wk[swz(n+1)];
            float2 v2 = wk[swz(n+2)], v3 = wk[swz(n+3)];
            oa[e] = make_float4(v0.x, v1.x, v2.x, v3.x);
            ob[e] = make_float4(v0.y, v1.y, v2.y, v3.y);
        }
    }
}

extern "C" void kernel_launch(void* const* d_in, const int* in_sizes, int n_in,
                              void* d_out, int out_size, void* d_ws, size_t ws_size,
                              hipStream_t stream)
{
    (void)n_in; (void)out_size; (void)ws_size;
    const float* x  = (const float*)d_in[0];
    const float* wg = (const float*)d_in[1];
    const float* wu = (const float*)d_in[2];
    const float* wd = (const float*)d_in[3];
    float2* wsp = (float2*)d_ws;          // 132*257 float2 = 271 KB used
    float*  out = (float*)d_out;

    const int rows = in_sizes[0] / 2048;  // 16384

    wf_prep<<<132, 64, 0, stream>>>(wg, wu, wd, wsp);
    bcffn<<<rows, 256, 0, stream>>>(x, wsp, out);
}